// Round 7
// baseline (280.386 us; speedup 1.0000x reference)
//
#include <hip/hip_runtime.h>

// Problem constants (from setup_inputs)
#define NB 8
#define NC 3
#define NT 32
#define NH 224
#define NW 224
#define DIFF 16
#define INV_SCALE (224.0f / 240.0f)   // in/out = 14/15

#define TILE_ROWS 16
#define TILES_PER_FRAME (NH / TILE_ROWS)   // 14
#define NFRAMES (NB * NC * NT)             // 768

// 8B loads at dword alignment (R6 proved 4B-aligned wide loads correct on gfx950)
typedef float float2a __attribute__((ext_vector_type(2), aligned(4)));

// R7: explicit-MLP test. Ledger: LDS(null), DMA-pipe(null), VMEM-count(null),
// width(null), occupancy(null); issue arithmetic = only ~14us/CU. Last live
// mechanism: exposed load latency (R4's VGPR=16 proved the compiler does NOT
// hoist loads across rows in carried loops; 16 serial {load->wait->lerp}
// stages x 400-900cy, L3 partially thrashed by 308MB/iter streams).
// Fix: rows made fully independent (no carry), ALL 32 dwordx2 loads issued
// in phase 1 into constant-indexed register arrays, consumed in phase 2.
// Taps and lerp order bit-identical to R5 -> absmax unchanged.
__global__ __launch_bounds__(256, 4) void shake_crop_mlp_kernel(
    const float* __restrict__ video,
    const int* __restrict__ shake_h,
    const int* __restrict__ shake_w,
    float* __restrict__ out)
{
    const int tid  = threadIdx.x;
    const int f    = blockIdx.x / TILES_PER_FRAME;   // frame index (b*C+c)*T + t
    const int tile = blockIdx.x - f * TILES_PER_FRAME;
    if (tid >= NW) return;            // 224 compute lanes; no barriers anywhere

    const int t  = f % NT;
    const int sh = shake_h[t];        // wave-uniform
    const int sw = shake_w[t];
    const int ybase = tile * TILE_ROWS;

    // Per-column horizontal weights (once per thread)
    const int x = tid;
    float ix = fminf(fmaxf((x + sw + 0.5f) * INV_SCALE - 0.5f, 0.0f), (float)(NW - 1));
    int   x0 = (int)ix;
    float fx = ix - (float)x0;
    const int  base = min(x0, NW - 2); // dwordx2 at base covers {x0, x1} for all lanes:
    const bool hi   = (x0 > base);     // x0<=222: taps = {base, base+1}; x0=223 (fx==0):
                                       // v00=v01=[223]=.y. Bit-identical to scalar taps.

    const float* fcol = video + (size_t)f * (NH * NW) + base;
    float* ocol = out + (size_t)f * (NH * NW) + (size_t)ybase * NW + x;
    const int ys = ybase + sh;

    // ---- Phase 1: row geometry + ALL 32 independent loads in flight ----
    float2a T[TILE_ROWS], B[TILE_ROWS];
    float   fy[TILE_ROWS];
    #pragma unroll
    for (int ry = 0; ry < TILE_ROWS; ++ry) {
        float iy = fminf(fmaxf((ys + ry + 0.5f) * INV_SCALE - 0.5f, 0.0f), (float)(NH - 1));
        int   y0 = (int)iy;            // wave-uniform
        fy[ry]   = iy - (float)y0;
        int   y1 = min(y0 + 1, NH - 1);
        T[ry] = *(const float2a*)(fcol + y0 * NW);   // independent
        B[ry] = *(const float2a*)(fcol + y1 * NW);   // independent
    }

    // ---- Phase 2: consume; lerp chain bit-identical to prior passing kernels ----
    #pragma unroll
    for (int ry = 0; ry < TILE_ROWS; ++ry) {
        float v00 = hi ? T[ry].y : T[ry].x;
        float v01 = T[ry].y;
        float v10 = hi ? B[ry].y : B[ry].x;
        float v11 = B[ry].y;

        float top = v00 + fx * (v01 - v00);
        float bot = v10 + fx * (v11 - v10);
        float v   = top + fy[ry] * (bot - top);
        ocol[(size_t)ry * NW] = fminf(fmaxf(v, 0.0f), 1.0f);   // coalesced 256B/wave
    }
}

extern "C" void kernel_launch(void* const* d_in, const int* in_sizes, int n_in,
                              void* d_out, int out_size, void* d_ws, size_t ws_size,
                              hipStream_t stream) {
    const float* video   = (const float*)d_in[0];
    const int*   shake_h = (const int*)d_in[1];
    const int*   shake_w = (const int*)d_in[2];
    float*       out     = (float*)d_out;

    const int grid = NFRAMES * TILES_PER_FRAME;   // 10752 blocks (same as R3/R5 for A/B)
    shake_crop_mlp_kernel<<<grid, 256, 0, stream>>>(video, shake_h, shake_w, out);
}

// Round 8
// 267.290 us; speedup vs baseline: 1.0490x; 1.0490x over previous
//
#include <hip/hip_runtime.h>

// Problem constants (from setup_inputs)
#define NB 8
#define NC 3
#define NT 32
#define NH 224
#define NW 224
#define DIFF 16
#define INV_SCALE (224.0f / 240.0f)   // in/out = 14/15

#define TILE_ROWS 16
#define TILES_PER_FRAME (NH / TILE_ROWS)   // 14
#define NFRAMES (NB * NC * NT)             // 768
#define NTILES (NFRAMES * TILES_PER_FRAME) // 10752
#define GRID 2048                          // 256 CU x 8 blocks, persistent

// R8: discriminating experiment — persistent grid-stride, ZERO barriers,
// body identical to R3 (fastest known at ~84us; bit-identical numerics).
// Ledger: 8 structures all land 84-105us with every pipe <40%. Two live
// theories: (1) per-lane TA address-processing floor (predicts: unchanged),
// (2) block launch/drain bound — 10752 blocks x ~2.5us lifetime needs
// ~105 launches/us; R7's 39% occupancy with no resource limiter points here
// (predicts: 55-65us). R2 tested persistence confounded with per-tile
// __syncthreads + DMA drains + 1280-block grid; this version has none.
__global__ __launch_bounds__(256) void shake_crop_persist_kernel(
    const float* __restrict__ video,
    const int* __restrict__ shake_h,
    const int* __restrict__ shake_w,
    float* __restrict__ out)
{
    const int tid = threadIdx.x;

    for (int tileIdx = blockIdx.x; tileIdx < NTILES; tileIdx += GRID) {
        const int f    = tileIdx / TILES_PER_FRAME;   // frame index (b*C+c)*T + t
        const int tile = tileIdx - f * TILES_PER_FRAME;

        if (tid < NW) {                 // uniform per wave except wave 3 (32/64 active)
            const int t  = f % NT;
            const int sh = shake_h[t];  // block-uniform -> scalar loads (L1-hot)
            const int sw = shake_w[t];
            const int ybase = tile * TILE_ROWS;

            // Per-column horizontal weights
            const int x = tid;
            float ix = fminf(fmaxf((x + sw + 0.5f) * INV_SCALE - 0.5f, 0.0f), (float)(NW - 1));
            int   x0 = (int)ix;
            float fx = ix - (float)x0;
            int   x1 = min(x0 + 1, NW - 1);

            const float* frame = video + (size_t)f * (NH * NW);
            float* ocol = out + (size_t)f * (NH * NW) + (size_t)ybase * NW + x;
            const int ys = ybase + sh;

            #pragma unroll
            for (int ry = 0; ry < TILE_ROWS; ++ry) {
                float iy = fminf(fmaxf((ys + ry + 0.5f) * INV_SCALE - 0.5f, 0.0f), (float)(NH - 1));
                int   y0 = (int)iy;     // wave-uniform
                float fy = iy - (float)y0;
                int   y1 = min(y0 + 1, NH - 1);
                const float* r0p = frame + y0 * NW;
                const float* r1p = frame + y1 * NW;

                float v00 = r0p[x0];    // 4 independent gathers, L1/L3-hot
                float v01 = r0p[x1];
                float v10 = r1p[x0];
                float v11 = r1p[x1];

                float top = v00 + fx * (v01 - v00);
                float bot = v10 + fx * (v11 - v10);
                float v   = top + fy * (bot - top);
                ocol[(size_t)ry * NW] = fminf(fmaxf(v, 0.0f), 1.0f);  // coalesced
            }
        }
        // no __syncthreads anywhere: loop iterations are fully independent,
        // compiler may overlap next tile's loads with this tile's stores
    }
}

extern "C" void kernel_launch(void* const* d_in, const int* in_sizes, int n_in,
                              void* d_out, int out_size, void* d_ws, size_t ws_size,
                              hipStream_t stream) {
    const float* video   = (const float*)d_in[0];
    const int*   shake_h = (const int*)d_in[1];
    const int*   shake_w = (const int*)d_in[2];
    float*       out     = (float*)d_out;

    shake_crop_persist_kernel<<<GRID, 256, 0, stream>>>(video, shake_h, shake_w, out);
}